// Round 4
// baseline (3487.436 us; speedup 1.0000x reference)
//
#include <hip/hip_runtime.h>
#include <hip/hip_bf16.h>

// Problem constants
#define B_ 2
#define T_ 1024
#define E_ 512
#define H_ 8
#define L_ 4
#define NT_ 32000
#define FF_ 2048
#define BT_ (B_*T_)              // 2048 rows
#define OFF_MEAN 65536000L       // B*NT*T
#define OFF_MAX  65537024L       // OFF_MEAN + B*E

typedef __attribute__((ext_vector_type(4))) float  f32x4;
typedef __attribute__((ext_vector_type(8))) short  short8;
typedef __attribute__((ext_vector_type(8))) __bf16 bf168;

__device__ __forceinline__ unsigned short f2b(float f) {          // f32 -> bf16 RNE
  union { float f; unsigned u; } x; x.f = f;
  unsigned r = x.u + 0x7FFFu + ((x.u >> 16) & 1u);
  return (unsigned short)(r >> 16);
}
__device__ __forceinline__ float b2f(unsigned short u) {
  union { float f; unsigned u; } x; x.u = ((unsigned)u) << 16; return x.f;
}

// ---- MFMA wrapper robust to builtin operand type (short8 vs bf16x8) ----
template<typename V>
__device__ __forceinline__ auto mfma_try(V a, V b, f32x4 c, int)
    -> decltype(__builtin_amdgcn_mfma_f32_16x16x32_bf16(a, b, c, 0, 0, 0)) {
  return __builtin_amdgcn_mfma_f32_16x16x32_bf16(a, b, c, 0, 0, 0);
}
template<typename V>
__device__ __forceinline__ f32x4 mfma_try(V a, V b, f32x4 c, long) {
  bf168 ac = __builtin_bit_cast(bf168, a);
  bf168 bc = __builtin_bit_cast(bf168, b);
  return __builtin_amdgcn_mfma_f32_16x16x32_bf16(ac, bc, c, 0, 0, 0);
}
__device__ __forceinline__ f32x4 MFMA(short8 a, short8 b, f32x4 c) {
  return mfma_try(a, b, c, 0);
}

// ---- block reduction (256 threads = 4 waves), OP: 0=sum 1=max ----
template<int OP>
__device__ __forceinline__ float blk_red(float v) {
  #pragma unroll
  for (int off = 32; off; off >>= 1) {
    float w = __shfl_xor(v, off);
    v = OP ? fmaxf(v, w) : (v + w);
  }
  __shared__ float buf[4];
  __syncthreads();                       // protect buf from a previous call
  if ((threadIdx.x & 63) == 0) buf[threadIdx.x >> 6] = v;
  __syncthreads();
  return OP ? fmaxf(fmaxf(buf[0], buf[1]), fmaxf(buf[2], buf[3]))
            : (buf[0] + buf[1] + buf[2] + buf[3]);
}

// =======================================================================
// Generic tiled MFMA GEMM, f32 in/out, bf16 compute (optionally split-bf16 B).
//   C = alpha * (A @ B) + bias  [, relu]
// A: (M,K) row-major, lda.   B: BTRANS ? (N,K) : (K,N), ldb.
// Batched over blockIdx.z: off = (z%8)*s?h + (z/8)*s?b  (strides 0 => unbatched)
// causal: skip blocks strictly above the diagonal (S = Q K^T).
// kcap: limit K-loop to m0+BM (PV with causal-zero P tail).
// All M,N multiples of 128; K multiples of 32 (no bounds checks needed).
// =======================================================================
constexpr int BMt = 128, BNt = 128, BKt = 32, BKP = 40;  // BKP: padded LDS stride

template<bool BTRANS, bool SPLITB, bool RELU>
__global__ __launch_bounds__(256)
void gemm_k(const float* __restrict__ A, int lda, long sAh, long sAb,
            const float* __restrict__ Bp, int ldb, long sBh, long sBb,
            float* __restrict__ C, int ldc, long sCh, long sCb,
            int K, float alpha, const float* __restrict__ bias,
            int causal, int kcap) {
  if (causal && blockIdx.x > blockIdx.y) return;   // fully-masked tile
  const int m0 = blockIdx.y * BMt, n0 = blockIdx.x * BNt;
  const int z = blockIdx.z, hz = z & 7, bz = z >> 3;
  const float* Ab = A  + (long)hz * sAh + (long)bz * sAb + (long)m0 * lda;
  const float* Bb = Bp + (long)hz * sBh + (long)bz * sBb;
  float*       Cb = C  + (long)hz * sCh + (long)bz * sCb;

  int Keff = K;
  if (kcap) { Keff = m0 + BMt; if (Keff > K) Keff = K; }

  __shared__ __align__(16) unsigned short As[BMt][BKP];
  __shared__ __align__(16) unsigned short Bs[BNt][BKP];
  __shared__ __align__(16) unsigned short Bs2[SPLITB ? BNt : 1][SPLITB ? BKP : 1];

  const int tid  = threadIdx.x;
  const int lane = tid & 63, wv = tid >> 6;
  const int wr = wv >> 1, wc = wv & 1;
  const int l15 = lane & 15, lh = lane >> 4;

  f32x4 acc[4][4];
  #pragma unroll
  for (int i = 0; i < 4; ++i)
    #pragma unroll
    for (int j = 0; j < 4; ++j) acc[i][j] = f32x4{0.f, 0.f, 0.f, 0.f};

  for (int k0 = 0; k0 < Keff; k0 += BKt) {
    { // stage A tile (rows of A), f32 -> bf16
      int r = tid >> 3, kq = (tid & 7) * 4;
      #pragma unroll
      for (int it = 0; it < 4; ++it) {
        const float4 vv = *(const float4*)(Ab + (long)(r + it * 32) * lda + k0 + kq);
        ushort4 u; u.x = f2b(vv.x); u.y = f2b(vv.y); u.z = f2b(vv.z); u.w = f2b(vv.w);
        *(ushort4*)&As[r + it * 32][kq] = u;
      }
    }
    if constexpr (BTRANS) { // B is (N,K): stage like A
      int r = tid >> 3, kq = (tid & 7) * 4;
      #pragma unroll
      for (int it = 0; it < 4; ++it) {
        const float4 vv = *(const float4*)(Bb + (long)(n0 + r + it * 32) * ldb + k0 + kq);
        ushort4 u; u.x = f2b(vv.x); u.y = f2b(vv.y); u.z = f2b(vv.z); u.w = f2b(vv.w);
        *(ushort4*)&Bs[r + it * 32][kq] = u;
      }
    } else {               // B is (K,N): stage transposed (coalesced along N)
      int n = tid & 127, ks = tid >> 7;
      #pragma unroll
      for (int it = 0; it < 16; ++it) {
        int kk = ks + it * 2;
        float vv = Bb[(long)(k0 + kk) * ldb + n0 + n];
        unsigned short hi = f2b(vv);
        Bs[n][kk] = hi;
        if constexpr (SPLITB) Bs2[n][kk] = f2b(vv - b2f(hi));
      }
    }
    __syncthreads();

    short8 af[4];
    #pragma unroll
    for (int mi = 0; mi < 4; ++mi)
      af[mi] = *(const short8*)&As[wr * 64 + mi * 16 + l15][lh * 8];
    #pragma unroll
    for (int ni = 0; ni < 4; ++ni) {
      short8 bfr = *(const short8*)&Bs[wc * 64 + ni * 16 + l15][lh * 8];
      #pragma unroll
      for (int mi = 0; mi < 4; ++mi)
        acc[mi][ni] = MFMA(af[mi], bfr, acc[mi][ni]);
    }
    if constexpr (SPLITB) {
      #pragma unroll
      for (int ni = 0; ni < 4; ++ni) {
        short8 bfr = *(const short8*)&Bs2[wc * 64 + ni * 16 + l15][lh * 8];
        #pragma unroll
        for (int mi = 0; mi < 4; ++mi)
          acc[mi][ni] = MFMA(af[mi], bfr, acc[mi][ni]);
      }
    }
    __syncthreads();
  }

  // epilogue: C/D layout col=lane&15, row=(lane>>4)*4+reg  [HW-verified]
  #pragma unroll
  for (int ni = 0; ni < 4; ++ni) {
    int col = n0 + wc * 64 + ni * 16 + l15;
    float bv = bias ? bias[col] : 0.f;
    #pragma unroll
    for (int mi = 0; mi < 4; ++mi) {
      #pragma unroll
      for (int j = 0; j < 4; ++j) {
        int row = m0 + wr * 64 + mi * 16 + lh * 4 + j;
        float o = alpha * acc[mi][ni][j] + bv;
        if (RELU) o = fmaxf(o, 0.f);
        Cb[(long)row * ldc + col] = o;
      }
    }
  }
}

// ---- embedding: h[r] = tok_emb[x[r]] + pos_emb[r % T] ----
__global__ __launch_bounds__(256)
void embed_k(const int* __restrict__ x, const float* __restrict__ tok,
             const float* __restrict__ pos, float* __restrict__ h) {
  int r = blockIdx.x, t = r & (T_ - 1);
  long xb = (long)x[r] * E_, tb = (long)t * E_, hb = (long)r * E_;
  int tid = threadIdx.x;
  h[hb + tid]       = tok[xb + tid]       + pos[tb + tid];
  h[hb + tid + 256] = tok[xb + tid + 256] + pos[tb + tid + 256];
}

// ---- causal softmax over rows of S (in-place, zeros past the diagonal) ----
__global__ __launch_bounds__(256)
void softmax_k(float* __restrict__ S) {
  int z = blockIdx.x, bh = z >> 10, i = z & (T_ - 1);
  float* row = S + ((long)bh << 20) + (long)i * T_;
  int n = i + 1, tid = threadIdx.x;
  float m = -INFINITY;
  for (int j = tid; j < n; j += 256) m = fmaxf(m, row[j]);
  m = blk_red<1>(m);
  float s = 0.f;
  for (int j = tid; j < n; j += 256) { float e = __expf(row[j] - m); row[j] = e; s += e; }
  s = blk_red<0>(s);
  float inv = 1.f / s;
  for (int j = tid; j < T_; j += 256) row[j] = (j < n) ? row[j] * inv : 0.f;
}

// ---- residual + layernorm, in-place on h: h = LN(in + h)*g + b ----
__global__ __launch_bounds__(256)
void ln_k(const float* __restrict__ in, float* __restrict__ h,
          const float* __restrict__ g, const float* __restrict__ bb) {
  long base = (long)blockIdx.x * E_;
  int tid = threadIdx.x;
  float x0 = in[base + tid]       + h[base + tid];
  float x1 = in[base + tid + 256] + h[base + tid + 256];
  float mean = blk_red<0>(x0 + x1) * (1.f / E_);
  float d0 = x0 - mean, d1 = x1 - mean;
  float var = blk_red<0>(d0 * d0 + d1 * d1) * (1.f / E_);
  float rs = rsqrtf(var + 1e-5f);
  h[base + tid]       = d0 * rs * g[tid]       + bb[tid];
  h[base + tid + 256] = d1 * rs * g[tid + 256] + bb[tid + 256];
}

// ---- emb mean/max partials over T chunks ----
__global__ __launch_bounds__(256)
void mm_part(const float* __restrict__ h, float* __restrict__ psum, float* __restrict__ pmax) {
  int tc = blockIdx.x, eh = blockIdx.y, b = blockIdx.z;
  int e = eh * 256 + threadIdx.x;
  float s = 0.f, mx = -INFINITY;
  for (int tt = 0; tt < 128; ++tt) {
    float v = h[(long)(b * T_ + tc * 128 + tt) * E_ + e];
    s += v; mx = fmaxf(mx, v);
  }
  int idx = (b * 8 + tc) * E_ + e;
  psum[idx] = s; pmax[idx] = mx;
}
__global__ __launch_bounds__(256)
void mm_comb(const float* __restrict__ psum, const float* __restrict__ pmax,
             float* __restrict__ out) {
  int u = blockIdx.x, b = u >> 1;
  int e = (u & 1) * 256 + threadIdx.x;
  float s = 0.f, mx = -INFINITY;
  for (int tc = 0; tc < 8; ++tc) {
    int idx = (b * 8 + tc) * E_ + e;
    s += psum[idx]; mx = fmaxf(mx, pmax[idx]);
  }
  out[OFF_MEAN + b * E_ + e] = s * (1.f / T_);
  out[OFF_MAX  + b * E_ + e] = mx;
}

// ---- column-wise LSE over per-batch logits viewed as (NT, T) row-major ----
__global__ __launch_bounds__(256)
void lse_part(const float* __restrict__ out, float* __restrict__ pm, float* __restrict__ ps) {
  const float* base = out + (long)blockIdx.y * NT_ * T_;
  int r0 = blockIdx.x * 256, tid = threadIdx.x;
  float m[4] = {-INFINITY, -INFINITY, -INFINITY, -INFINITY};
  float s[4] = {0.f, 0.f, 0.f, 0.f};
  for (int rr = 0; rr < 256; ++rr) {
    long ro = (long)(r0 + rr) * T_;
    #pragma unroll
    for (int c = 0; c < 4; ++c) {
      float x = base[ro + tid + c * 256];
      if (x > m[c]) { s[c] = s[c] * __expf(m[c] - x) + 1.f; m[c] = x; }
      else          { s[c] += __expf(x - m[c]); }
    }
  }
  #pragma unroll
  for (int c = 0; c < 4; ++c) {
    long idx = ((long)blockIdx.y * 125 + blockIdx.x) * T_ + tid + c * 256;
    pm[idx] = m[c]; ps[idx] = s[c];
  }
}
__global__ __launch_bounds__(256)
void lse_comb(const float* __restrict__ pm, const float* __restrict__ ps,
              float* __restrict__ lse) {
  int b = blockIdx.y, t = blockIdx.x * 256 + threadIdx.x;
  float m = -INFINITY;
  for (int c = 0; c < 125; ++c) m = fmaxf(m, pm[((long)b * 125 + c) * T_ + t]);
  float s = 0.f;
  for (int c = 0; c < 125; ++c) {
    long idx = ((long)b * 125 + c) * T_ + t;
    s += ps[idx] * __expf(pm[idx] - m);
  }
  lse[b * T_ + t] = m + logf(s);
}

// ---- out[i] -= lse[b, i mod T]  (vectorized) ----
__global__ __launch_bounds__(256)
void sub_k(float* __restrict__ out, const float* __restrict__ lse) {
  const long n4 = (long)B_ * NT_ * T_ / 4;
  for (long i = (long)blockIdx.x * blockDim.x + threadIdx.x; i < n4;
       i += (long)gridDim.x * blockDim.x) {
    long f = i * 4;
    int b = (f >= (long)NT_ * T_) ? 1 : 0;
    int t0 = (int)(f & (T_ - 1));
    float4 v = ((float4*)out)[i];
    const float4 lv = *(const float4*)&lse[b * T_ + t0];
    v.x -= lv.x; v.y -= lv.y; v.z -= lv.z; v.w -= lv.w;
    ((float4*)out)[i] = v;
  }
}

extern "C" void kernel_launch(void* const* d_in, const int* in_sizes, int n_in,
                              void* d_out, int out_size, void* d_ws, size_t ws_size,
                              hipStream_t stream) {
  (void)in_sizes; (void)n_in; (void)out_size; (void)ws_size;
  const int*   x   = (const int*)  d_in[0];
  const float* tok = (const float*)d_in[1];
  const float* pos = (const float*)d_in[2];
  const float* Wq  = (const float*)d_in[3];
  const float* Wk  = (const float*)d_in[4];
  const float* Wv  = (const float*)d_in[5];
  const float* Wu  = (const float*)d_in[6];
  const float* bu  = (const float*)d_in[7];
  const float* g1  = (const float*)d_in[8];
  const float* b1n = (const float*)d_in[9];
  const float* g2  = (const float*)d_in[10];
  const float* b2n = (const float*)d_in[11];
  const float* W1  = (const float*)d_in[12];
  const float* bf1 = (const float*)d_in[13];
  const float* W2  = (const float*)d_in[14];
  const float* bf2 = (const float*)d_in[15];
  const float* Wp  = (const float*)d_in[16];
  const float* bp  = (const float*)d_in[17];
  float* out = (float*)d_out;

  // ---- scratch layout ----
  // d_ws (small, ~27.3 MB): persistent per-layer activations + reductions.
  float* w    = (float*)d_ws;
  float* h    = w;                  // 1,048,576
  float* u    = h    + 1048576;     // 1,048,576
  float* f1   = u    + 1048576;     // 4,194,304
  float* pm   = f1   + 4194304;     // 256,000
  float* ps   = pm   + 256000;      // 256,000
  float* lse  = ps   + 256000;      // 2,048
  float* psum = lse  + 2048;        // 8,192
  float* pmax = psum + 8192;        // 8,192  (total 6,821,888 floats)
  // d_out (262 MB) doubles as big scratch until the logits GEMM overwrites it:
  //   S: 16 x 1024 x 1024 f32   at out[0 .. 16,777,216)
  //   q/kk/v/o: 8,388,608 each  at out[16,777,216 .. 50,331,648)  (< 65,536,000)
  float* S    = out;
  float* q    = out + 16777216;
  float* kk   = q   + 8388608;
  float* v    = kk  + 8388608;
  float* o    = v   + 8388608;

  const float aS = 0.04419417382415922f;  // 512^-0.5 (q and k each /E^0.25)
  const long  sQ = (long)T_ * H_ * E_;    // per-batch stride in q/k/v/o

  embed_k<<<BT_, 256, 0, stream>>>(x, tok, pos, h);

  for (int l = 0; l < L_; ++l) {
    const float* Wq_l  = Wq  + (long)l * E_ * H_ * E_;
    const float* Wk_l  = Wk  + (long)l * E_ * H_ * E_;
    const float* Wv_l  = Wv  + (long)l * E_ * H_ * E_;
    const float* Wu_l  = Wu  + (long)l * H_ * E_ * E_;
    const float* bu_l  = bu  + l * E_;
    const float* g1_l  = g1  + l * E_;
    const float* b1_l  = b1n + l * E_;
    const float* g2_l  = g2  + l * E_;
    const float* b2_l  = b2n + l * E_;
    const float* W1_l  = W1  + (long)l * E_ * FF_;
    const float* bf1_l = bf1 + l * FF_;
    const float* W2_l  = W2  + (long)l * FF_ * E_;
    const float* bf2_l = bf2 + l * E_;

    // q/k/v = h @ W  (split-bf16 weights)
    gemm_k<false,true,false><<<dim3(32,16,1),256,0,stream>>>(
        h, E_,0,0,  Wq_l, H_*E_,0,0,  q, H_*E_,0,0,  E_, 1.f, nullptr, 0,0);
    gemm_k<false,true,false><<<dim3(32,16,1),256,0,stream>>>(
        h, E_,0,0,  Wk_l, H_*E_,0,0,  kk, H_*E_,0,0,  E_, 1.f, nullptr, 0,0);
    gemm_k<false,true,false><<<dim3(32,16,1),256,0,stream>>>(
        h, E_,0,0,  Wv_l, H_*E_,0,0,  v, H_*E_,0,0,  E_, 1.f, nullptr, 0,0);
    // S = (Q K^T)/sqrt(E), batched over 16 (b,h), causal block-skip
    gemm_k<true,false,false><<<dim3(8,8,16),256,0,stream>>>(
        q, H_*E_, 512, sQ,  kk, H_*E_, 512, sQ,
        S, T_, 1L<<20, 8L<<20,  E_, aS, nullptr, 1,0);
    softmax_k<<<B_*H_*T_,256,0,stream>>>(S);
    // o = P @ V, K-loop capped at query block (P zero past diagonal)
    gemm_k<false,false,false><<<dim3(4,8,16),256,0,stream>>>(
        S, T_, 1L<<20, 8L<<20,  v, H_*E_, 512, sQ,
        o, H_*E_, 512, sQ,  T_, 1.f, nullptr, 0,1);
    // unify + bias, then h = LN(u + h)
    gemm_k<false,true,false><<<dim3(4,16,1),256,0,stream>>>(
        o, H_*E_,0,0,  Wu_l, E_,0,0,  u, E_,0,0,  H_*E_, 1.f, bu_l, 0,0);
    ln_k<<<BT_,256,0,stream>>>(u, h, g1_l, b1_l);
    // FF
    gemm_k<false,true,true><<<dim3(16,16,1),256,0,stream>>>(
        h, E_,0,0,  W1_l, FF_,0,0,  f1, FF_,0,0,  E_, 1.f, bf1_l, 0,0);
    gemm_k<false,true,false><<<dim3(4,16,1),256,0,stream>>>(
        f1, FF_,0,0,  W2_l, E_,0,0,  u, E_,0,0,  FF_, 1.f, bf2_l, 0,0);
    ln_k<<<BT_,256,0,stream>>>(u, h, g2_l, b2_l);
  }

  // emb mean/max of final h
  mm_part<<<dim3(8,2,B_),256,0,stream>>>(h, psum, pmax);
  mm_comb<<<4,256,0,stream>>>(psum, pmax, out);

  // logits = h @ Wp + bp, row-major (2048,32000) == flat (B,NT,T) layout
  gemm_k<false,false,false><<<dim3(250,16,1),256,0,stream>>>(
      h, E_,0,0,  Wp, NT_,0,0,  out, NT_,0,0,  E_, 1.f, bp, 0,0);

  // log_softmax over nt: column-wise LSE of per-batch (NT,T) view, then subtract
  lse_part<<<dim3(125,B_),256,0,stream>>>(out, pm, ps);
  lse_comb<<<dim3(4,B_),256,0,stream>>>(pm, ps, lse);
  sub_k<<<2048,256,0,stream>>>(out, lse);
}